// Round 4
// baseline (402.116 us; speedup 1.0000x reference)
//
#include <hip/hip_runtime.h>
#include <math.h>

// ---------------------------------------------------------------------------
// K=1,c=1 -> softmax over singleton axis == 1 -> gw branch dead. Pipeline:
//   sp   = silu(bn(spdconv(x)))            (16,512,512), row/col 511 zero
//   F    = fft2(sp) ; keep ky 0..511, kx 0..255
//   tpl  = {lowRe,lowIm,highRe,highIm}     4 planes of (16,256,256)
//   y_c  = conv3x3(tpl_c)+sdi_b ; p_c = cumprod_b(y_c)
//   feat2= relu(bn_gen(silu(bn_fuse(sum_c fuse_w[c]*p_c))))
//   out[b,o,i,j] = feat2[b,i,j]*w_final[o] (16,64,256,256)
//
// FFTs: radix-8 register FFT (512 = 8*8*8), 1 wave per FFT, 8 FFTs/block.
// S3/S4 fused: conv3x3 via LDS halo tiles + cumprod + activations + expand.
// ---------------------------------------------------------------------------

#define PI_F 3.14159265358979323846f

struct cpx { float re, im; };
__device__ __forceinline__ cpx cadd(cpx a, cpx b){ return {a.re+b.re, a.im+b.im}; }
__device__ __forceinline__ cpx csub(cpx a, cpx b){ return {a.re-b.re, a.im-b.im}; }
__device__ __forceinline__ cpx cmul(cpx a, cpx b){ return {a.re*b.re - a.im*b.im, a.re*b.im + a.im*b.re}; }
__device__ __forceinline__ cpx cnegi(cpx a){ return {a.im, -a.re}; }   // a * (-i)

// DFT8, decimation-in-frequency: reg m -> X[brev3(m)], brev3 = {0,4,2,6,1,5,3,7}
__device__ __forceinline__ void dft8_dif(cpx* a) {
    const float C = 0.70710678118654752440f;
    cpx t0=cadd(a[0],a[4]), t1=cadd(a[1],a[5]), t2=cadd(a[2],a[6]), t3=cadd(a[3],a[7]);
    cpx s0=csub(a[0],a[4]), s1=csub(a[1],a[5]), s2=csub(a[2],a[6]), s3=csub(a[3],a[7]);
    s1 = (cpx){ C*(s1.re + s1.im), C*(s1.im - s1.re) };   // * W8^1
    s2 = cnegi(s2);                                        // * W8^2
    s3 = (cpx){ C*(s3.im - s3.re), -C*(s3.re + s3.im) };   // * W8^3
    cpx u0=cadd(t0,t2), u1=cadd(t1,t3), u2=csub(t0,t2), u3=cnegi(csub(t1,t3));
    cpx v0=cadd(s0,s2), v1=cadd(s1,s3), v2=csub(s0,s2), v3=cnegi(csub(s1,s3));
    a[0]=cadd(u0,u1); a[1]=csub(u0,u1); a[2]=cadd(u2,u3); a[3]=csub(u2,u3);
    a[4]=cadd(v0,v1); a[5]=csub(v0,v1); a[6]=cadd(v2,v3); a[7]=csub(v2,v3);
}

// a[m] *= p^{brev3(m)}
__device__ __forceinline__ void twiddle_brev(cpx* a, cpx p) {
    cpx w = p;
    a[4] = cmul(a[4], w); w = cmul(w, p);
    a[2] = cmul(a[2], w); w = cmul(w, p);
    a[6] = cmul(a[6], w); w = cmul(w, p);
    a[1] = cmul(a[1], w); w = cmul(w, p);
    a[5] = cmul(a[5], w); w = cmul(w, p);
    a[3] = cmul(a[3], w); w = cmul(w, p);
    a[7] = cmul(a[7], w);
}

// 512-pt FFT. a[m] in: x[t + 64*m]. out: a[m] = X[t + 64*brev3(m)].
// bR/bI: per-wave scratch, 576 floats each. 4 __syncthreads inside.
__device__ __forceinline__ void fft512_r8(cpx* a, float* bR, float* bI, int t) {
    float sn, cs;
    dft8_dif(a);
    __sincosf(-2.0f * PI_F * (float)t / 512.0f, &sn, &cs);
    twiddle_brev(a, (cpx){cs, sn});
    bR[0*69 + t] = a[0].re; bI[0*69 + t] = a[0].im;
    bR[4*69 + t] = a[1].re; bI[4*69 + t] = a[1].im;
    bR[2*69 + t] = a[2].re; bI[2*69 + t] = a[2].im;
    bR[6*69 + t] = a[3].re; bI[6*69 + t] = a[3].im;
    bR[1*69 + t] = a[4].re; bI[1*69 + t] = a[4].im;
    bR[5*69 + t] = a[5].re; bI[5*69 + t] = a[5].im;
    bR[3*69 + t] = a[6].re; bI[3*69 + t] = a[6].im;
    bR[7*69 + t] = a[7].re; bI[7*69 + t] = a[7].im;
    __syncthreads();
    int k0 = t & 7, t0 = t >> 3;
    cpx b[8];
#pragma unroll
    for (int i = 0; i < 8; i++) {
        b[i].re = bR[k0*69 + t0 + 8*i];
        b[i].im = bI[k0*69 + t0 + 8*i];
    }
    __syncthreads();
    dft8_dif(b);
    __sincosf(-2.0f * PI_F * (float)t0 / 64.0f, &sn, &cs);
    twiddle_brev(b, (cpx){cs, sn});
    bR[(0*8 + k0)*9 + t0] = b[0].re; bI[(0*8 + k0)*9 + t0] = b[0].im;
    bR[(4*8 + k0)*9 + t0] = b[1].re; bI[(4*8 + k0)*9 + t0] = b[1].im;
    bR[(2*8 + k0)*9 + t0] = b[2].re; bI[(2*8 + k0)*9 + t0] = b[2].im;
    bR[(6*8 + k0)*9 + t0] = b[3].re; bI[(6*8 + k0)*9 + t0] = b[3].im;
    bR[(1*8 + k0)*9 + t0] = b[4].re; bI[(1*8 + k0)*9 + t0] = b[4].im;
    bR[(5*8 + k0)*9 + t0] = b[5].re; bI[(5*8 + k0)*9 + t0] = b[5].im;
    bR[(3*8 + k0)*9 + t0] = b[6].re; bI[(3*8 + k0)*9 + t0] = b[6].im;
    bR[(7*8 + k0)*9 + t0] = b[7].re; bI[(7*8 + k0)*9 + t0] = b[7].im;
    __syncthreads();
    int rowb = t * 9;
#pragma unroll
    for (int i = 0; i < 8; i++) {
        a[i].re = bR[rowb + i];
        a[i].im = bI[rowb + i];
    }
    __syncthreads();   // scratch free for reuse after this
    dft8_dif(a);
}

// ---- S1: spdconv fused + row FFT; RT[b][kx<256][y] (float2), 64B stores ----
__global__ __launch_bounds__(512) void fft_rows_spd8(
        const float* __restrict__ x, const float* __restrict__ w4,
        const float* __restrict__ g1, const float* __restrict__ b1,
        float2* __restrict__ RT) {
    __shared__ __align__(16) float pool[9216];
    int tid = threadIdx.x;
    int w = tid >> 6, t = tid & 63;
    float* bR = pool + w * 1152;
    float* bI = bR + 576;
    int row = blockIdx.x * 8 + w;        // b*512 + y
    int b = row >> 9, yy = row & 511;
    float w0 = w4[0], w1 = w4[1], w2c = w4[2], w3 = w4[3];
    float scale = g1[0] * rsqrtf(1.f + 1e-5f);
    float bias  = b1[0];
    cpx a[8];
#pragma unroll
    for (int m = 0; m < 8; m++) {
        int p = t + 64 * m;
        float v = 0.f;
        if (yy < 511 && p < 511) {
            const float* r0 = x + ((size_t)b * 1022 + 2 * yy) * 1022 + 2 * p;
            float2 e = *(const float2*)r0;
            float2 o = *(const float2*)(r0 + 1022);
            v = w0 * e.x + w1 * o.x + w2c * e.y + w3 * o.y;
            v = v * scale + bias;
            v = v / (1.f + expf(-v));
        }
        a[m] = (cpx){v, 0.f};
    }
    fft512_r8(a, bR, bI, t);
    // keep k = t + 64*brev3(m) < 256 -> m in {0,4,2,6}
    float2* tile = (float2*)pool;        // [256][pad 9] float2 = 18 KB
    tile[(t +   0) * 9 + w] = make_float2(a[0].re, a[0].im);
    tile[(t +  64) * 9 + w] = make_float2(a[4].re, a[4].im);
    tile[(t + 128) * 9 + w] = make_float2(a[2].re, a[2].im);
    tile[(t + 192) * 9 + w] = make_float2(a[6].re, a[6].im);
    __syncthreads();
    int y0 = (blockIdx.x & 63) * 8;      // 64 blocks per b
    float2* dst = RT + (size_t)(b * 256) * 512 + y0;
#pragma unroll
    for (int r = 0; r < 4; r++) {
        int e = tid + 512 * r;           // 0..2047
        int k = e >> 3, ww = e & 7;
        dst[(size_t)k * 512 + ww] = tile[k * 9 + ww];
    }
}

// ---- S2: column FFT; reads RT coalesced; tpl planes [c][b][ky][kx] --------
__global__ __launch_bounds__(512) void fft_cols8(
        const float2* __restrict__ RT, float* __restrict__ tpl) {
    __shared__ __align__(16) float pool[9216];
    int tid = threadIdx.x;
    int w = tid >> 6, t = tid & 63;
    float* bR = pool + w * 1152;
    float* bI = bR + 576;
    int b = blockIdx.x >> 5;             // 32 blocks per b
    int kx0 = (blockIdx.x & 31) * 8;
    const float2* src = RT + (size_t)(b * 256 + kx0 + w) * 512;
    cpx a[8];
#pragma unroll
    for (int m = 0; m < 8; m++) {
        float2 v = src[t + 64 * m];
        a[m] = (cpx){v.x, v.y};
    }
    fft512_r8(a, bR, bI, t);
    float2* tile = (float2*)pool;        // [512][pad 9] float2 = 36,864 B
    tile[(t +   0) * 9 + w] = make_float2(a[0].re, a[0].im);
    tile[(t +  64) * 9 + w] = make_float2(a[4].re, a[4].im);
    tile[(t + 128) * 9 + w] = make_float2(a[2].re, a[2].im);
    tile[(t + 192) * 9 + w] = make_float2(a[6].re, a[6].im);
    tile[(t + 256) * 9 + w] = make_float2(a[1].re, a[1].im);
    tile[(t + 320) * 9 + w] = make_float2(a[5].re, a[5].im);
    tile[(t + 384) * 9 + w] = make_float2(a[3].re, a[3].im);
    tile[(t + 448) * 9 + w] = make_float2(a[7].re, a[7].im);
    __syncthreads();
    const size_t P = (size_t)16 * 256 * 256;
#pragma unroll
    for (int r = 0; r < 8; r++) {
        int e = tid + 512 * r;           // 0..4095
        int ky = e >> 3, ww = e & 7;
        float2 v = tile[ky * 9 + ww];
        if (ky < 256) {
            size_t idx = (size_t)(b * 256 + ky) * 256 + kx0 + ww;
            tpl[idx]     = v.x;          // low.real
            tpl[P + idx] = v.y;          // low.imag
        } else {
            size_t idx = (size_t)(b * 256 + (ky - 256)) * 256 + kx0 + ww;
            tpl[2*P + idx] = v.x;        // high.real
            tpl[3*P + idx] = v.y;        // high.imag
        }
    }
}

// ---- S3+S4 fused: conv3x3 (LDS halo tiles) + cumprod + activ + expand -----
// grid = 256 tiles x 2 o-groups; block 256 threads = one 16x16 pixel tile.
__global__ __launch_bounds__(256) void conv_cum_expand(
        const float* __restrict__ tpl,
        const float* __restrict__ sdiw, const float* __restrict__ sdib,
        const float* __restrict__ fw, const float* __restrict__ fg,
        const float* __restrict__ fb, const float* __restrict__ gg,
        const float* __restrict__ gb, const float* __restrict__ wf,
        float* __restrict__ out) {
    __shared__ float tile[4][18][20];     // +pad
    int tt  = threadIdx.x;
    int og  = blockIdx.x & 1;
    int tix = blockIdx.x >> 1;            // 0..255
    int ti0 = (tix >> 4) * 16, tj0 = (tix & 15) * 16;
    int tin = tt >> 4, tjn = tt & 15;
    int gi_c = ti0 + tin, gj_c = tj0 + tjn;

    float w9[9];
#pragma unroll
    for (int k = 0; k < 9; k++) w9[k] = sdiw[k];
    float bias = sdib[0];
    float inv = rsqrtf(1.f + 1e-5f);
    float fscale = fg[0] * inv, fbias = fb[0];
    float gscale = gg[0] * inv, gbias = gb[0];
    float fw4[4] = {fw[0], fw[1], fw[2], fw[3]};
    float wfv[32];
#pragma unroll
    for (int oo = 0; oo < 32; oo++) wfv[oo] = wf[og * 32 + oo];

    const size_t P = (size_t)16 * 65536;
    float p[4] = {1.f, 1.f, 1.f, 1.f};
    float* obase = out + (size_t)gi_c * 256 + gj_c;

    for (int b = 0; b < 16; b++) {
        // load 4 halo tiles (18x18) for this b
#pragma unroll
        for (int it = 0; it < 6; it++) {
            int id = it * 256 + tt;
            if (id < 1296) {
                int c  = id / 324;
                int rm = id - c * 324;
                int r  = rm / 18;
                int cc = rm - r * 18;
                int gi = ti0 + r - 1, gj = tj0 + cc - 1;
                float v = 0.f;
                if (gi >= 0 && gi < 256 && gj >= 0 && gj < 256)
                    v = tpl[c * P + (size_t)b * 65536 + gi * 256 + gj];
                tile[c][r][cc] = v;
            }
        }
        __syncthreads();
        float f = 0.f;
#pragma unroll
        for (int c = 0; c < 4; c++) {
            float acc = bias;
#pragma unroll
            for (int di = 0; di < 3; di++)
#pragma unroll
                for (int dj = 0; dj < 3; dj++)
                    acc += w9[di * 3 + dj] * tile[c][tin + di][tjn + dj];
            p[c] *= acc;
            f += fw4[c] * p[c];
        }
        float bn = f * fscale + fbias;
        float ft = bn / (1.f + expf(-bn));
        float g  = ft * gscale + gbias;
        float f2 = fmaxf(g, 0.f);
        float* ob = obase + (size_t)(b * 64 + og * 32) * 65536;
#pragma unroll
        for (int oo = 0; oo < 32; oo++)
            ob[(size_t)oo * 65536] = f2 * wfv[oo];
        __syncthreads();
    }
}

extern "C" void kernel_launch(void* const* d_in, const int* in_sizes, int n_in,
                              void* d_out, int out_size, void* d_ws, size_t ws_size,
                              hipStream_t stream) {
    const float* x    = (const float*)d_in[0];
    const float* wspd = (const float*)d_in[9];
    const float* bng  = (const float*)d_in[10];
    const float* bnb  = (const float*)d_in[11];
    const float* sdiw = (const float*)d_in[12];
    const float* sdib = (const float*)d_in[13];
    const float* fw   = (const float*)d_in[14];
    const float* fg   = (const float*)d_in[15];
    const float* fb   = (const float*)d_in[16];
    const float* gg   = (const float*)d_in[17];
    const float* gb   = (const float*)d_in[18];
    const float* wf   = (const float*)d_in[19];
    float* out = (float*)d_out;

    // 32 MiB workspace, recycled:
    float2* RT  = (float2*)d_ws;                          // [0, 16M)
    float*  tpl = (float*)d_ws + (size_t)4 * 1024 * 1024; // [16M, 32M)

    fft_rows_spd8  <<<dim3(1024), dim3(512), 0, stream>>>(x, wspd, bng, bnb, RT);
    fft_cols8      <<<dim3(512),  dim3(512), 0, stream>>>(RT, tpl);
    conv_cum_expand<<<dim3(512),  dim3(256), 0, stream>>>(tpl, sdiw, sdib, fw, fg,
                                                          fb, gg, gb, wf, out);
}